// Round 9
// baseline (267.245 us; speedup 1.0000x reference)
//
#include <hip/hip_runtime.h>
#include <cstdint>
#include <cstddef>

#define BATCH  8192
#define IN_N   256
#define OUT_N  256
#define LAT_N  128
#define SLABS  129                 // 128 latent slabs + 1 bw slab
#define KT     (SLABS * IN_N)      // 33024 = total K in elements
#define KT16   (KT / 16)           // 2064 k-tiles of 16
#define SPLITK 4

typedef _Float16 h8 __attribute__((ext_vector_type(8)));
typedef _Float16 h4 __attribute__((ext_vector_type(4)));
typedef _Float16 h2 __attribute__((ext_vector_type(2)));
typedef float    f16v __attribute__((ext_vector_type(16)));
typedef float    f4v  __attribute__((ext_vector_type(4)));

#define AS1 __attribute__((address_space(1)))
#define AS3 __attribute__((address_space(3)))
#define WAITVM0 asm volatile("s_waitcnt vmcnt(0)" ::: "memory")
#define WAITVM2 asm volatile("s_waitcnt vmcnt(2)" ::: "memory")
#define WAITVM4 asm volatile("s_waitcnt vmcnt(4)" ::: "memory")

// ws layout (bytes) — identical total footprint to the proven baseline (56,770,560 B)
#define WS_BP    0                 // packed B: 8 nt * 2064 kt * 64 lane * 8 halves * 2B = 16908288
#define WS_XH    16908288          // + 8192*256*2 = 4194304
#define WS_LT    21102592          // + 129*8192*2 = 2113536
#define WS_PARTS 23216128          // + 4 * 8192*256*4 = 33554432  -> total 56770560

// ---------------- K1 (fused prep) — unchanged from R7 (coalesced, proven).
#define PR_T1   516
#define PR_L1   580
#define PR_X1   1604
#define PR_O1   1608
#define PR_B1   2632
__global__ void k_prep(const float* __restrict__ Ww, const float* __restrict__ bw,
                       const float* __restrict__ x,  const float* __restrict__ latent,
                       const float* __restrict__ Wb, const float* __restrict__ bb,
                       _Float16* __restrict__ Bp, _Float16* __restrict__ Xh,
                       _Float16* __restrict__ LT, float* __restrict__ part0) {
    __shared__ _Float16 smemh[16512];       // 33024 B
    const int bid = blockIdx.x;
    const int t   = threadIdx.x;

    if (bid < PR_T1) {
        // ---- W transpose + pack. tile[64][256] f16 = 32KB.
        _Float16* tile = smemh;
        const int k0 = bid * 64;
#pragma unroll
        for (int j = 0; j < 16; ++j) {
            int idx = j * 256 + t;          // 4096 float4 slots = 64 rows x 64 f4
            int row = idx >> 6, col = (idx & 63) * 4;
            int k = k0 + row;
            const float* src = (k < LAT_N * IN_N)
                             ? Ww + (size_t)k * 256 + col
                             : bw + (size_t)(k - LAT_N * IN_N) * 256 + col;
            float4 v = *(const float4*)src;
            h4 o;
            o[0] = (_Float16)v.x; o[1] = (_Float16)v.y;
            o[2] = (_Float16)v.z; o[3] = (_Float16)v.w;
            *(h4*)(tile + row * 256 + col) = o;
        }
        __syncthreads();
        const int tl = t & 31;
#pragma unroll
        for (int j = 0; j < 4; ++j) {
            int stid = j * 8 + (t >> 5);    // 0..31 subtiles
            int kt_l = stid >> 3, nt = stid & 7;
            int kt16 = bid * 4 + kt_l;
            _Float16* dst = Bp + ((size_t)(nt * KT16 + kt16) * 64) * 8;
#pragma unroll
            for (int kh = 0; kh < 2; ++kh) {
                h8 v;
#pragma unroll
                for (int h = 0; h < 8; ++h)
                    v[h] = tile[(kt_l * 16 + kh * 8 + h) * 256 + nt * 32 + tl];
                *(h8*)(dst + (size_t)(kh * 32 + tl) * 8) = v;
            }
        }
    } else if (bid < PR_L1) {
        // ---- latent transpose via 128x129 LDS tile
        _Float16* t2 = smemh;
        const int b0 = (bid - PR_T1) * 128;
#pragma unroll
        for (int j = 0; j < 16; ++j) {
            int idx = j * 256 + t;          // 4096 float4 slots = 128 b-rows x 32 f4
            int b = idx >> 5, l = (idx & 31) * 4;
            float4 v = *(const float4*)(latent + (size_t)(b0 + b) * 128 + l);
            t2[(l + 0) * 129 + b] = (_Float16)v.x;
            t2[(l + 1) * 129 + b] = (_Float16)v.y;
            t2[(l + 2) * 129 + b] = (_Float16)v.z;
            t2[(l + 3) * 129 + b] = (_Float16)v.w;
        }
        __syncthreads();
#pragma unroll
        for (int j = 0; j < 32; ++j) {
            int idx = j * 256 + t;          // 8192 h2 slots = 128 l-rows x 64 h2
            int l = idx >> 6, bb2 = (idx & 63) * 2;
            h2 w;
            w[0] = t2[l * 129 + bb2];
            w[1] = t2[l * 129 + bb2 + 1];
            *(h2*)(LT + (size_t)l * BATCH + b0 + bb2) = w;
        }
    } else if (bid < PR_X1) {
        // ---- x -> f16, 8 elems/thread
        const int cb = bid - PR_L1;
        int i = (cb * 256 + t) * 8;
        float4 v0 = *(const float4*)(x + i);
        float4 v1 = *(const float4*)(x + i + 4);
        h8 o;
        o[0] = (_Float16)v0.x; o[1] = (_Float16)v0.y;
        o[2] = (_Float16)v0.z; o[3] = (_Float16)v0.w;
        o[4] = (_Float16)v1.x; o[5] = (_Float16)v1.y;
        o[6] = (_Float16)v1.z; o[7] = (_Float16)v1.w;
        *(h8*)(Xh + i) = o;
    } else if (bid < PR_O1) {
        // ---- ones row l=128 of LT
        const int ob = bid - PR_X1;
        int base = ob * 2048 + t * 8;
        h8 o;
#pragma unroll
        for (int h = 0; h < 8; ++h) o[h] = (_Float16)1.0f;
        *(h8*)(LT + (size_t)LAT_N * BATCH + base) = o;
    } else {
        // ---- bias into split-0 partial
        float* lat = (float*)smemh;         // [8][128] f32 = 4KB
        const int b0 = (bid - PR_O1) * 8;   // 1024 blocks
#pragma unroll
        for (int j = 0; j < 4; ++j) {
            int idx = t + 256 * j;          // 0..1023
            int rr = idx >> 7, l = idx & 127;
            lat[rr * 128 + l] = latent[(size_t)(b0 + rr) * 128 + l];
        }
        __syncthreads();
        const int o = t;
        float acc[8];
        float bbv = bb[o];
#pragma unroll
        for (int rr = 0; rr < 8; ++rr) acc[rr] = bbv;
        for (int l = 0; l < 128; ++l) {
            float w = Wb[l * 256 + o];
#pragma unroll
            for (int rr = 0; rr < 8; ++rr) acc[rr] += lat[rr * 128 + l] * w;
        }
#pragma unroll
        for (int rr = 0; rr < 8; ++rr) part0[(size_t)(b0 + rr) * 256 + o] = acc[rr];
    }
}

// ---------------- K2: main GEMM. R8 pipeline + 64x64 wave tiles.
// R8 diagnosis: MfmaUtil 43% with 0 bank conflicts and clean FETCH; per step the
// block ds_reads 64KB for 16KB staged (4 waves per wn re-read identical fragments)
// -> LDS read BW ~500-750 cy/step vs 128 cy MFMA: LDS-amplification-bound.
// FIX: wave tile 32x128 -> 64x64 (2 row-tiles x 2 col-tiles). Per kt16 a wave reads
// 2 B-frags and issues 4 MFMAs (was 4:4) -> LDS reads halve to 32KB/step.
// Cost: A-in-regs doubles (xv[2][16] = 128 VGPR); arch ~170 + 64 acc ~= 235 <= 256.
// REGISTER SAFETY: __launch_bounds__(512,1) — an 8-wave block forces 2 waves/SIMD,
// so the allocator is HARD-capped at 256 total regs (launchability), while
// min-waves=1 avoids the clamp-to-granule spill pathology (R3/R4/R5).
// vmcnt: 2 latent-scalar prefetches per slab -> slab-start wait = vmcnt(4)
// (stage[s+1](2 oldest) must drain; sn(2)+stage[s+2](2) may remain); else vmcnt(2).
__global__ __launch_bounds__(512, 1) void k_gemm(const _Float16* __restrict__ Bp,
                                                 const _Float16* __restrict__ Xh,
                                                 const _Float16* __restrict__ LT,
                                                 float* __restrict__ parts) {
    __shared__ __align__(16) _Float16 Bs[4 * 8192];   // 64 KB: 4 bufs x (2 kt16 x 8 nt x 1KB)

    const int bid   = blockIdx.x;           // 256 blocks
    const int ks    = bid & 3;
    const int m_blk = bid >> 2;             // 0..63
    const int m0    = m_blk * 128;
    const int slab0 = (ks == 0) ? 0 : 33 + 32 * (ks - 1);
    const int nslab = (ks == 0) ? 33 : 32;  // 33 + 3*32 = 129

    const int tid = threadIdx.x, wid = tid >> 6, lane = tid & 63;
    const int l32 = lane & 31, khalf = lane >> 5;
    const int wm = wid >> 2, wn = wid & 3;  // 2M x 4N wave grid, tile 64x64
    const int mrow0 = m0 + wm * 64 + l32;   // row-tile 0
    const int mrow1 = mrow0 + 32;           // row-tile 1

    // ---- A fragment rows into registers (2 row-tiles x 16 k16-tiles x h8)
    h8 xv0[16], xv1[16];
    const _Float16* xp0 = Xh + (size_t)mrow0 * IN_N + khalf * 8;
    const _Float16* xp1 = Xh + (size_t)mrow1 * IN_N + khalf * 8;
#pragma unroll
    for (int k = 0; k < 16; ++k) {
        xv0[k] = *(const h8*)(xp0 + k * 16);
        xv1[k] = *(const h8*)(xp1 + k * 16);
    }

    // latent scalars for slab 0
    const _Float16* ltp = LT + (size_t)slab0 * BATCH;
    _Float16 sc0 = ltp[mrow0], sc1 = ltp[mrow1];

    // ---- B staging setup: 16 chunks/step (kt_l in {0,1} x nt in 0..7), 2 per wave
    const int chunk0 = wid * 2;
    const int ktl0 = chunk0 >> 3, nt0 = chunk0 & 7;
    const char* Bgb = (const char*)Bp;

#define STAGE(bufidx, ktg)                                                                 \
    do {                                                                                   \
        const char* g0_ = Bgb + (((size_t)(nt0 * KT16 + (ktg) + ktl0)) << 10) + (lane << 4);     \
        const char* g1_ = Bgb + (((size_t)((nt0 + 1) * KT16 + (ktg) + ktl0)) << 10) + (lane << 4); \
        _Float16* l0_ = Bs + (bufidx) * 8192 + chunk0 * 512;                               \
        __builtin_amdgcn_global_load_lds((const AS1 void*)g0_, (AS3 void*)l0_, 16, 0, 0);  \
        __builtin_amdgcn_global_load_lds((const AS1 void*)g1_, (AS3 void*)(l0_ + 512), 16, 0, 0); \
    } while (0)

    f16v acc00, acc01, acc10, acc11;        // [row-tile][col-tile]
#pragma unroll
    for (int r = 0; r < 16; ++r) { acc00[r] = 0.f; acc01[r] = 0.f; acc10[r] = 0.f; acc11[r] = 0.f; }

#define KSTEP(bufc, sl)                                                                    \
    _Pragma("unroll")                                                                      \
    for (int j = 0; j < 2; ++j) {                                                          \
        const int kx = (((sl) * 2 + j) & 15);                                              \
        h8 a0 = xv0[kx] * s80;                                                             \
        h8 a1 = xv1[kx] * s81;                                                             \
        const _Float16* bb = Bs + (bufc) * 8192 + j * 4096 + wn * 1024 + (lane << 3);      \
        h8 b0 = *(const h8*)(bb);                                                          \
        h8 b1 = *(const h8*)(bb + 512);                                                    \
        acc00 = __builtin_amdgcn_mfma_f32_32x32x16_f16(a0, b0, acc00, 0, 0, 0);            \
        acc01 = __builtin_amdgcn_mfma_f32_32x32x16_f16(a0, b1, acc01, 0, 0, 0);            \
        acc10 = __builtin_amdgcn_mfma_f32_32x32x16_f16(a1, b0, acc10, 0, 0, 0);            \
        acc11 = __builtin_amdgcn_mfma_f32_32x32x16_f16(a1, b1, acc11, 0, 0, 0);            \
    }

    const int kb = slab0 * 16;              // base kt16 of this K-split

    // ---- prologue: stage steps 0,1 into bufs 0,1; wait buf0 complete
    STAGE(0, kb + 0);
    STAGE(1, kb + 2);
    WAITVM2;
    __builtin_amdgcn_s_barrier();
    asm volatile("" ::: "memory");

    // ---- main loop: slabs 0 .. nslab-2 (stages always valid, LT prefetch each slab)
    for (int s0 = 0; s0 < nslab - 1; ++s0) {
        _Float16 sn0 = ltp[(size_t)(s0 + 1) * BATCH + mrow0];   // 2 VM ops (covered by vmcnt(4))
        _Float16 sn1 = ltp[(size_t)(s0 + 1) * BATCH + mrow1];
        h8 s80, s81;
#pragma unroll
        for (int h = 0; h < 8; ++h) { s80[h] = sc0; s81[h] = sc1; }
        const int ktg0 = kb + s0 * 16;
#pragma unroll
        for (int sl = 0; sl < 8; ++sl) {
            STAGE((sl + 2) & 3, ktg0 + (sl + 2) * 2);
            KSTEP(sl & 3, sl);
            if (sl == 0) WAITVM4; else WAITVM2;
            __builtin_amdgcn_s_barrier();
            asm volatile("" ::: "memory");
        }
        sc0 = sn0; sc1 = sn1;
    }

    // ---- last slab (peeled): no stages past the end, drain at sl==6
    {
        h8 s80, s81;
#pragma unroll
        for (int h = 0; h < 8; ++h) { s80[h] = sc0; s81[h] = sc1; }
        const int ktg0 = kb + (nslab - 1) * 16;
#pragma unroll
        for (int sl = 0; sl < 8; ++sl) {
            if (sl < 6) STAGE((sl + 2) & 3, ktg0 + (sl + 2) * 2);
            KSTEP(sl & 3, sl);
            if (sl < 7) {
                if (sl == 6) WAITVM0; else WAITVM2;
                __builtin_amdgcn_s_barrier();
                asm volatile("" ::: "memory");
            }
        }
    }

    // ---- epilogue: write partials; split 0 accumulates onto pre-written bias
    float* dst = parts + (size_t)ks * ((size_t)BATCH * OUT_N);
    const int rowb0 = m0 + wm * 64;
#define EPI(rowb, u, accv)                                                                 \
    {                                                                                      \
        int col = wn * 64 + (u) * 32 + l32;                                                \
        _Pragma("unroll")                                                                  \
        for (int r = 0; r < 16; ++r) {                                                     \
            int row = (rowb) + (r & 3) + 8 * (r >> 2) + 4 * khalf;                         \
            size_t off = (size_t)row * OUT_N + col;                                        \
            if (ks == 0) dst[off] += accv[r];                                              \
            else         dst[off] = accv[r];                                               \
        }                                                                                  \
    }
    EPI(rowb0,      0, acc00); EPI(rowb0,      1, acc01);
    EPI(rowb0 + 32, 0, acc10); EPI(rowb0 + 32, 1, acc11);
#undef EPI
#undef KSTEP
#undef STAGE
}

// ---------------- K3: out = sum of 4 partials
__global__ void k_reduce(const float* __restrict__ parts, float* __restrict__ out) {
    int i = (blockIdx.x * 256 + threadIdx.x) * 4;
    f4v s = *(const f4v*)(parts + i);
    s += *(const f4v*)(parts + 2097152 + i);
    s += *(const f4v*)(parts + 2 * 2097152 + i);
    s += *(const f4v*)(parts + 3 * 2097152 + i);
    *(f4v*)(out + i) = s;
}

extern "C" void kernel_launch(void* const* d_in, const int* in_sizes, int n_in,
                              void* d_out, int out_size, void* d_ws, size_t ws_size,
                              hipStream_t stream) {
    const float* x      = (const float*)d_in[0];
    const float* latent = (const float*)d_in[1];
    const float* Ww     = (const float*)d_in[2];
    const float* bw     = (const float*)d_in[3];
    const float* Wb     = (const float*)d_in[4];
    const float* bb     = (const float*)d_in[5];

    char* ws = (char*)d_ws;
    _Float16* Bp    = (_Float16*)(ws + WS_BP);
    _Float16* Xh    = (_Float16*)(ws + WS_XH);
    _Float16* LT    = (_Float16*)(ws + WS_LT);
    float*    parts = (float*)(ws + WS_PARTS);
    float*    out   = (float*)d_out;

    k_prep<<<PR_B1, 256, 0, stream>>>(Ww, bw, x, latent, Wb, bb, Bp, Xh, LT, parts);
    k_gemm<<<256, 512, 0, stream>>>(Bp, Xh, LT, parts);
    k_reduce<<<2048, 256, 0, stream>>>(parts, out);
}

// Round 10
// 260.761 us; speedup vs baseline: 1.0249x; 1.0249x over previous
//
#include <hip/hip_runtime.h>
#include <cstdint>
#include <cstddef>

#define BATCH  8192
#define IN_N   256
#define OUT_N  256
#define LAT_N  128
#define SLABS  129                 // 128 latent slabs + 1 bw slab
#define KT     (SLABS * IN_N)      // 33024 = total K in elements
#define KT16   (KT / 16)           // 2064 k-tiles of 16
#define SPLITK 4

typedef _Float16 h8 __attribute__((ext_vector_type(8)));
typedef _Float16 h4 __attribute__((ext_vector_type(4)));
typedef _Float16 h2 __attribute__((ext_vector_type(2)));
typedef float    f16v __attribute__((ext_vector_type(16)));
typedef float    f4v  __attribute__((ext_vector_type(4)));

#define AS1 __attribute__((address_space(1)))
#define AS3 __attribute__((address_space(3)))
#define WAITVM0 asm volatile("s_waitcnt vmcnt(0)" ::: "memory")
#define WAITVM4 asm volatile("s_waitcnt vmcnt(4)" ::: "memory")
#define WAITVM6 asm volatile("s_waitcnt vmcnt(6)" ::: "memory")

// ws layout (bytes) — identical total footprint to the proven baseline (56,770,560 B)
#define WS_BP    0                 // packed B: 8 nt * 2064 kt * 64 lane * 8 halves * 2B = 16908288
#define WS_XH    16908288          // + 8192*256*2 = 4194304
#define WS_LT    21102592          // + 129*8192*2 = 2113536
#define WS_PARTS 23216128          // + 4 * 8192*256*4 = 33554432  -> total 56770560

// ---------------- K1 (fused prep) — unchanged from R7 (coalesced, proven).
#define PR_T1   516
#define PR_L1   580
#define PR_X1   1604
#define PR_O1   1608
#define PR_B1   2632
__global__ void k_prep(const float* __restrict__ Ww, const float* __restrict__ bw,
                       const float* __restrict__ x,  const float* __restrict__ latent,
                       const float* __restrict__ Wb, const float* __restrict__ bb,
                       _Float16* __restrict__ Bp, _Float16* __restrict__ Xh,
                       _Float16* __restrict__ LT, float* __restrict__ part0) {
    __shared__ _Float16 smemh[16512];       // 33024 B
    const int bid = blockIdx.x;
    const int t   = threadIdx.x;

    if (bid < PR_T1) {
        // ---- W transpose + pack. tile[64][256] f16 = 32KB.
        _Float16* tile = smemh;
        const int k0 = bid * 64;
#pragma unroll
        for (int j = 0; j < 16; ++j) {
            int idx = j * 256 + t;          // 4096 float4 slots = 64 rows x 64 f4
            int row = idx >> 6, col = (idx & 63) * 4;
            int k = k0 + row;
            const float* src = (k < LAT_N * IN_N)
                             ? Ww + (size_t)k * 256 + col
                             : bw + (size_t)(k - LAT_N * IN_N) * 256 + col;
            float4 v = *(const float4*)src;
            h4 o;
            o[0] = (_Float16)v.x; o[1] = (_Float16)v.y;
            o[2] = (_Float16)v.z; o[3] = (_Float16)v.w;
            *(h4*)(tile + row * 256 + col) = o;
        }
        __syncthreads();
        const int tl = t & 31;
#pragma unroll
        for (int j = 0; j < 4; ++j) {
            int stid = j * 8 + (t >> 5);    // 0..31 subtiles
            int kt_l = stid >> 3, nt = stid & 7;
            int kt16 = bid * 4 + kt_l;
            _Float16* dst = Bp + ((size_t)(nt * KT16 + kt16) * 64) * 8;
#pragma unroll
            for (int kh = 0; kh < 2; ++kh) {
                h8 v;
#pragma unroll
                for (int h = 0; h < 8; ++h)
                    v[h] = tile[(kt_l * 16 + kh * 8 + h) * 256 + nt * 32 + tl];
                *(h8*)(dst + (size_t)(kh * 32 + tl) * 8) = v;
            }
        }
    } else if (bid < PR_L1) {
        // ---- latent transpose via 128x129 LDS tile
        _Float16* t2 = smemh;
        const int b0 = (bid - PR_T1) * 128;
#pragma unroll
        for (int j = 0; j < 16; ++j) {
            int idx = j * 256 + t;          // 4096 float4 slots = 128 b-rows x 32 f4
            int b = idx >> 5, l = (idx & 31) * 4;
            float4 v = *(const float4*)(latent + (size_t)(b0 + b) * 128 + l);
            t2[(l + 0) * 129 + b] = (_Float16)v.x;
            t2[(l + 1) * 129 + b] = (_Float16)v.y;
            t2[(l + 2) * 129 + b] = (_Float16)v.z;
            t2[(l + 3) * 129 + b] = (_Float16)v.w;
        }
        __syncthreads();
#pragma unroll
        for (int j = 0; j < 32; ++j) {
            int idx = j * 256 + t;          // 8192 h2 slots = 128 l-rows x 64 h2
            int l = idx >> 6, bb2 = (idx & 63) * 2;
            h2 w;
            w[0] = t2[l * 129 + bb2];
            w[1] = t2[l * 129 + bb2 + 1];
            *(h2*)(LT + (size_t)l * BATCH + b0 + bb2) = w;
        }
    } else if (bid < PR_X1) {
        // ---- x -> f16, 8 elems/thread
        const int cb = bid - PR_L1;
        int i = (cb * 256 + t) * 8;
        float4 v0 = *(const float4*)(x + i);
        float4 v1 = *(const float4*)(x + i + 4);
        h8 o;
        o[0] = (_Float16)v0.x; o[1] = (_Float16)v0.y;
        o[2] = (_Float16)v0.z; o[3] = (_Float16)v0.w;
        o[4] = (_Float16)v1.x; o[5] = (_Float16)v1.y;
        o[6] = (_Float16)v1.z; o[7] = (_Float16)v1.w;
        *(h8*)(Xh + i) = o;
    } else if (bid < PR_O1) {
        // ---- ones row l=128 of LT
        const int ob = bid - PR_X1;
        int base = ob * 2048 + t * 8;
        h8 o;
#pragma unroll
        for (int h = 0; h < 8; ++h) o[h] = (_Float16)1.0f;
        *(h8*)(LT + (size_t)LAT_N * BATCH + base) = o;
    } else {
        // ---- bias into split-0 partial
        float* lat = (float*)smemh;         // [8][128] f32 = 4KB
        const int b0 = (bid - PR_O1) * 8;   // 1024 blocks
#pragma unroll
        for (int j = 0; j < 4; ++j) {
            int idx = t + 256 * j;          // 0..1023
            int rr = idx >> 7, l = idx & 127;
            lat[rr * 128 + l] = latent[(size_t)(b0 + rr) * 128 + l];
        }
        __syncthreads();
        const int o = t;
        float acc[8];
        float bbv = bb[o];
#pragma unroll
        for (int rr = 0; rr < 8; ++rr) acc[rr] = bbv;
        for (int l = 0; l < 128; ++l) {
            float w = Wb[l * 256 + o];
#pragma unroll
            for (int rr = 0; rr < 8; ++rr) acc[rr] += lat[rr * 128 + l] * w;
        }
#pragma unroll
        for (int rr = 0; rr < 8; ++rr) part0[(size_t)(b0 + rr) * 256 + o] = acc[rr];
    }
}

// ---------------- K2: main GEMM. R9 + 4-kt16 steps (half the barriers).
// R8->R9 null (halved LDS reads, same 150-155us) killed the LDS-BW theory.
// Correct cycle model (32x32x16 MFMA ~32cy/SIMD chip-saturated, m119): per step
// per SIMD = 512cy MFMA vs 1450cy observed -> ~900cy/step of chain+barrier wall,
// PER-STEP not per-byte (that's why fewer bytes changed nothing). vmcnt latency
// ruled out (budget ~2 steps >> 300cy L2).
// FIX: step 2 kt16 -> 4 kt16 (32KB staged): steps 256->128, per-step MFMA 512->1024cy,
// longer unbroken ds_read/MFMA runs for the compiler to interleave. Ring = 4 bufs
// x 32KB = 128KB LDS (fits 160KB at 1 block/CU). Stage = 4 loads/wave/step.
// vmcnt: steady WAITVM4 (stage s+2 in flight); slab-start WAITVM6 (+2 latent);
// prologue WAITVM4; tail 4->0. Geometry/regs unchanged from R9 (64x64 wave tiles,
// bounds(512,1) — the no-clamp no-spill regime).
__global__ __launch_bounds__(512, 1) void k_gemm(const _Float16* __restrict__ Bp,
                                                 const _Float16* __restrict__ Xh,
                                                 const _Float16* __restrict__ LT,
                                                 float* __restrict__ parts) {
    __shared__ __align__(16) _Float16 Bs[4 * 16384];  // 128 KB: 4 bufs x (4 kt16 x 8 nt x 1KB)

    const int bid   = blockIdx.x;           // 256 blocks
    const int ks    = bid & 3;
    const int m_blk = bid >> 2;             // 0..63
    const int m0    = m_blk * 128;
    const int slab0 = (ks == 0) ? 0 : 33 + 32 * (ks - 1);
    const int nslab = (ks == 0) ? 33 : 32;  // 33 + 3*32 = 129

    const int tid = threadIdx.x, wid = tid >> 6, lane = tid & 63;
    const int l32 = lane & 31, khalf = lane >> 5;
    const int wm = wid >> 2, wn = wid & 3;  // 2M x 4N wave grid, tile 64x64
    const int mrow0 = m0 + wm * 64 + l32;   // row-tile 0
    const int mrow1 = mrow0 + 32;           // row-tile 1

    // ---- A fragment rows into registers (2 row-tiles x 16 k16-tiles x h8)
    h8 xv0[16], xv1[16];
    const _Float16* xp0 = Xh + (size_t)mrow0 * IN_N + khalf * 8;
    const _Float16* xp1 = Xh + (size_t)mrow1 * IN_N + khalf * 8;
#pragma unroll
    for (int k = 0; k < 16; ++k) {
        xv0[k] = *(const h8*)(xp0 + k * 16);
        xv1[k] = *(const h8*)(xp1 + k * 16);
    }

    // latent scalars for slab 0
    const _Float16* ltp = LT + (size_t)slab0 * BATCH;
    _Float16 sc0 = ltp[mrow0], sc1 = ltp[mrow1];

    // ---- B staging: 32 chunks/step (kt_l in 0..3 x nt in 0..7), 4 per wave
    const int chunk0 = wid * 4;
    const char* Bgb = (const char*)Bp;

#define STAGE(bufidx, ktg)                                                                 \
    _Pragma("unroll")                                                                      \
    for (int i_ = 0; i_ < 4; ++i_) {                                                       \
        const int c_   = chunk0 + i_;                                                      \
        const int ktl_ = c_ >> 3, nt_ = c_ & 7;                                            \
        const char* g_ = Bgb + (((size_t)(nt_ * KT16 + (ktg) + ktl_)) << 10) + (lane << 4);\
        _Float16* l_ = Bs + (bufidx) * 16384 + c_ * 512;                                   \
        __builtin_amdgcn_global_load_lds((const AS1 void*)g_, (AS3 void*)l_, 16, 0, 0);    \
    }

    f16v acc00, acc01, acc10, acc11;        // [row-tile][col-tile]
#pragma unroll
    for (int r = 0; r < 16; ++r) { acc00[r] = 0.f; acc01[r] = 0.f; acc10[r] = 0.f; acc11[r] = 0.f; }

#define KSTEP(bufc, sl)                                                                    \
    _Pragma("unroll")                                                                      \
    for (int j = 0; j < 4; ++j) {                                                          \
        const int kx = (((sl) * 4 + j) & 15);                                              \
        h8 a0 = xv0[kx] * s80;                                                             \
        h8 a1 = xv1[kx] * s81;                                                             \
        const _Float16* bb = Bs + (bufc) * 16384 + j * 4096 + wn * 1024 + (lane << 3);     \
        h8 b0 = *(const h8*)(bb);                                                          \
        h8 b1 = *(const h8*)(bb + 512);                                                    \
        acc00 = __builtin_amdgcn_mfma_f32_32x32x16_f16(a0, b0, acc00, 0, 0, 0);            \
        acc01 = __builtin_amdgcn_mfma_f32_32x32x16_f16(a0, b1, acc01, 0, 0, 0);            \
        acc10 = __builtin_amdgcn_mfma_f32_32x32x16_f16(a1, b0, acc10, 0, 0, 0);            \
        acc11 = __builtin_amdgcn_mfma_f32_32x32x16_f16(a1, b1, acc11, 0, 0, 0);            \
    }

    const int kb = slab0 * 16;              // base kt16 of this K-split

    // ---- prologue: stage steps 0,1 into bufs 0,1; wait buf0 complete (oldest 4 of 8)
    STAGE(0, kb + 0);
    STAGE(1, kb + 4);
    WAITVM4;
    __builtin_amdgcn_s_barrier();
    asm volatile("" ::: "memory");

    // ---- main loop: slabs 0 .. nslab-2 (4 steps/slab; stages always valid)
    for (int s0 = 0; s0 < nslab - 1; ++s0) {
        _Float16 sn0 = ltp[(size_t)(s0 + 1) * BATCH + mrow0];   // 2 VM ops (covered by WAITVM6)
        _Float16 sn1 = ltp[(size_t)(s0 + 1) * BATCH + mrow1];
        h8 s80, s81;
#pragma unroll
        for (int h = 0; h < 8; ++h) { s80[h] = sc0; s81[h] = sc1; }
        const int ktg0 = kb + s0 * 16;
#pragma unroll
        for (int sl = 0; sl < 4; ++sl) {
            STAGE((sl + 2) & 3, ktg0 + (sl + 2) * 4);
            KSTEP(sl, sl);
            if (sl == 0) WAITVM6; else WAITVM4;
            __builtin_amdgcn_s_barrier();
            asm volatile("" ::: "memory");
        }
        sc0 = sn0; sc1 = sn1;
    }

    // ---- last slab (peeled): stages only for sl<2 (steps 2,3); drain at sl==2
    {
        h8 s80, s81;
#pragma unroll
        for (int h = 0; h < 8; ++h) { s80[h] = sc0; s81[h] = sc1; }
        const int ktg0 = kb + (nslab - 1) * 16;
#pragma unroll
        for (int sl = 0; sl < 4; ++sl) {
            if (sl < 2) STAGE((sl + 2) & 3, ktg0 + (sl + 2) * 4);
            KSTEP(sl, sl);
            if (sl < 3) {
                if (sl == 2) WAITVM0; else WAITVM4;
                __builtin_amdgcn_s_barrier();
                asm volatile("" ::: "memory");
            }
        }
    }

    // ---- epilogue: write partials; split 0 accumulates onto pre-written bias
    float* dst = parts + (size_t)ks * ((size_t)BATCH * OUT_N);
    const int rowb0 = m0 + wm * 64;
#define EPI(rowb, u, accv)                                                                 \
    {                                                                                      \
        int col = wn * 64 + (u) * 32 + l32;                                                \
        _Pragma("unroll")                                                                  \
        for (int r = 0; r < 16; ++r) {                                                     \
            int row = (rowb) + (r & 3) + 8 * (r >> 2) + 4 * khalf;                         \
            size_t off = (size_t)row * OUT_N + col;                                        \
            if (ks == 0) dst[off] += accv[r];                                              \
            else         dst[off] = accv[r];                                               \
        }                                                                                  \
    }
    EPI(rowb0,      0, acc00); EPI(rowb0,      1, acc01);
    EPI(rowb0 + 32, 0, acc10); EPI(rowb0 + 32, 1, acc11);
#undef EPI
#undef KSTEP
#undef STAGE
}

// ---------------- K3: out = sum of 4 partials
__global__ void k_reduce(const float* __restrict__ parts, float* __restrict__ out) {
    int i = (blockIdx.x * 256 + threadIdx.x) * 4;
    f4v s = *(const f4v*)(parts + i);
    s += *(const f4v*)(parts + 2097152 + i);
    s += *(const f4v*)(parts + 2 * 2097152 + i);
    s += *(const f4v*)(parts + 3 * 2097152 + i);
    *(f4v*)(out + i) = s;
}

extern "C" void kernel_launch(void* const* d_in, const int* in_sizes, int n_in,
                              void* d_out, int out_size, void* d_ws, size_t ws_size,
                              hipStream_t stream) {
    const float* x      = (const float*)d_in[0];
    const float* latent = (const float*)d_in[1];
    const float* Ww     = (const float*)d_in[2];
    const float* bw     = (const float*)d_in[3];
    const float* Wb     = (const float*)d_in[4];
    const float* bb     = (const float*)d_in[5];

    char* ws = (char*)d_ws;
    _Float16* Bp    = (_Float16*)(ws + WS_BP);
    _Float16* Xh    = (_Float16*)(ws + WS_XH);
    _Float16* LT    = (_Float16*)(ws + WS_LT);
    float*    parts = (float*)(ws + WS_PARTS);
    float*    out   = (float*)d_out;

    k_prep<<<PR_B1, 256, 0, stream>>>(Ww, bw, x, latent, Wb, bb, Bp, Xh, LT, parts);
    k_gemm<<<256, 512, 0, stream>>>(Bp, Xh, LT, parts);
    k_reduce<<<2048, 256, 0, stream>>>(parts, out);
}

// Round 11
// 253.361 us; speedup vs baseline: 1.0548x; 1.0292x over previous
//
#include <hip/hip_runtime.h>
#include <cstdint>
#include <cstddef>

#define BATCH  8192
#define IN_N   256
#define OUT_N  256
#define LAT_N  128
#define SLABS  129                 // 128 latent slabs + 1 bw slab
#define KT     (SLABS * IN_N)      // 33024 = total K in elements
#define KT16   (KT / 16)           // 2064 k-tiles of 16
#define SPLITK 4

typedef _Float16 h8 __attribute__((ext_vector_type(8)));
typedef _Float16 h4 __attribute__((ext_vector_type(4)));
typedef _Float16 h2 __attribute__((ext_vector_type(2)));
typedef float    f16v __attribute__((ext_vector_type(16)));
typedef float    f4v  __attribute__((ext_vector_type(4)));

#define AS1 __attribute__((address_space(1)))
#define AS3 __attribute__((address_space(3)))
#define WAITVM0 asm volatile("s_waitcnt vmcnt(0)" ::: "memory")
#define WAITVM2 asm volatile("s_waitcnt vmcnt(2)" ::: "memory")
#define WAITVM4 asm volatile("s_waitcnt vmcnt(4)" ::: "memory")

// ws layout (bytes) — identical total footprint to the proven baseline (56,770,560 B)
#define WS_BP    0                 // packed B: 8 nt * 2064 kt * 64 lane * 8 halves * 2B = 16908288
#define WS_XH    16908288          // + 8192*256*2 = 4194304
#define WS_LT    21102592          // + 129*8192*2 = 2113536
#define WS_PARTS 23216128          // + 4 * 8192*256*4 = 33554432  -> total 56770560

// ---------------- K1 (fused prep) — unchanged from R7 (coalesced, proven).
#define PR_T1   516
#define PR_L1   580
#define PR_X1   1604
#define PR_O1   1608
#define PR_B1   2632
__global__ void k_prep(const float* __restrict__ Ww, const float* __restrict__ bw,
                       const float* __restrict__ x,  const float* __restrict__ latent,
                       const float* __restrict__ Wb, const float* __restrict__ bb,
                       _Float16* __restrict__ Bp, _Float16* __restrict__ Xh,
                       _Float16* __restrict__ LT, float* __restrict__ part0) {
    __shared__ _Float16 smemh[16512];       // 33024 B
    const int bid = blockIdx.x;
    const int t   = threadIdx.x;

    if (bid < PR_T1) {
        // ---- W transpose + pack. tile[64][256] f16 = 32KB.
        _Float16* tile = smemh;
        const int k0 = bid * 64;
#pragma unroll
        for (int j = 0; j < 16; ++j) {
            int idx = j * 256 + t;          // 4096 float4 slots = 64 rows x 64 f4
            int row = idx >> 6, col = (idx & 63) * 4;
            int k = k0 + row;
            const float* src = (k < LAT_N * IN_N)
                             ? Ww + (size_t)k * 256 + col
                             : bw + (size_t)(k - LAT_N * IN_N) * 256 + col;
            float4 v = *(const float4*)src;
            h4 o;
            o[0] = (_Float16)v.x; o[1] = (_Float16)v.y;
            o[2] = (_Float16)v.z; o[3] = (_Float16)v.w;
            *(h4*)(tile + row * 256 + col) = o;
        }
        __syncthreads();
        const int tl = t & 31;
#pragma unroll
        for (int j = 0; j < 4; ++j) {
            int stid = j * 8 + (t >> 5);    // 0..31 subtiles
            int kt_l = stid >> 3, nt = stid & 7;
            int kt16 = bid * 4 + kt_l;
            _Float16* dst = Bp + ((size_t)(nt * KT16 + kt16) * 64) * 8;
#pragma unroll
            for (int kh = 0; kh < 2; ++kh) {
                h8 v;
#pragma unroll
                for (int h = 0; h < 8; ++h)
                    v[h] = tile[(kt_l * 16 + kh * 8 + h) * 256 + nt * 32 + tl];
                *(h8*)(dst + (size_t)(kh * 32 + tl) * 8) = v;
            }
        }
    } else if (bid < PR_L1) {
        // ---- latent transpose via 128x129 LDS tile
        _Float16* t2 = smemh;
        const int b0 = (bid - PR_T1) * 128;
#pragma unroll
        for (int j = 0; j < 16; ++j) {
            int idx = j * 256 + t;          // 4096 float4 slots = 128 b-rows x 32 f4
            int b = idx >> 5, l = (idx & 31) * 4;
            float4 v = *(const float4*)(latent + (size_t)(b0 + b) * 128 + l);
            t2[(l + 0) * 129 + b] = (_Float16)v.x;
            t2[(l + 1) * 129 + b] = (_Float16)v.y;
            t2[(l + 2) * 129 + b] = (_Float16)v.z;
            t2[(l + 3) * 129 + b] = (_Float16)v.w;
        }
        __syncthreads();
#pragma unroll
        for (int j = 0; j < 32; ++j) {
            int idx = j * 256 + t;          // 8192 h2 slots = 128 l-rows x 64 h2
            int l = idx >> 6, bb2 = (idx & 63) * 2;
            h2 w;
            w[0] = t2[l * 129 + bb2];
            w[1] = t2[l * 129 + bb2 + 1];
            *(h2*)(LT + (size_t)l * BATCH + b0 + bb2) = w;
        }
    } else if (bid < PR_X1) {
        // ---- x -> f16, 8 elems/thread
        const int cb = bid - PR_L1;
        int i = (cb * 256 + t) * 8;
        float4 v0 = *(const float4*)(x + i);
        float4 v1 = *(const float4*)(x + i + 4);
        h8 o;
        o[0] = (_Float16)v0.x; o[1] = (_Float16)v0.y;
        o[2] = (_Float16)v0.z; o[3] = (_Float16)v0.w;
        o[4] = (_Float16)v1.x; o[5] = (_Float16)v1.y;
        o[6] = (_Float16)v1.z; o[7] = (_Float16)v1.w;
        *(h8*)(Xh + i) = o;
    } else if (bid < PR_O1) {
        // ---- ones row l=128 of LT
        const int ob = bid - PR_X1;
        int base = ob * 2048 + t * 8;
        h8 o;
#pragma unroll
        for (int h = 0; h < 8; ++h) o[h] = (_Float16)1.0f;
        *(h8*)(LT + (size_t)LAT_N * BATCH + base) = o;
    } else {
        // ---- bias into split-0 partial
        float* lat = (float*)smemh;         // [8][128] f32 = 4KB
        const int b0 = (bid - PR_O1) * 8;   // 1024 blocks
#pragma unroll
        for (int j = 0; j < 4; ++j) {
            int idx = t + 256 * j;          // 0..1023
            int rr = idx >> 7, l = idx & 127;
            lat[rr * 128 + l] = latent[(size_t)(b0 + rr) * 128 + l];
        }
        __syncthreads();
        const int o = t;
        float acc[8];
        float bbv = bb[o];
#pragma unroll
        for (int rr = 0; rr < 8; ++rr) acc[rr] = bbv;
        for (int l = 0; l < 128; ++l) {
            float w = Wb[l * 256 + o];
#pragma unroll
            for (int rr = 0; rr < 8; ++rr) acc[rr] += lat[rr * 128 + l] * w;
        }
#pragma unroll
        for (int rr = 0; rr < 8; ++rr) part0[(size_t)(b0 + rr) * 256 + o] = acc[rr];
    }
}

// ---------------- K2: main GEMM. R9 pipeline, 256-thread blocks, 2 blocks/CU.
// R8-R10 ledger: MfmaUtil stuck 42-45% with LDS reads halved (R9 null), barriers
// halved (R10 null), L2/vmcnt/spill excluded. Remaining cause is STRUCTURAL:
// 1 block/CU -> each SIMD's 2 waves are same-block, barrier-locked -> post-barrier
// serial ds_read->mul->issue window leaves the MFMA pipe empty with nothing to
// fill it. Fix = restore 2 INDEPENDENT blocks/CU (the m114 mechanism that made
// R2/R7 work): 256 thr (4 waves, 2Mx2N, same 64x64 wave tiles as R9), block tile
// 128x128, grid 512 = 64m x 2nb x 4ks. Per-wave code identical to R9 (~188 regs)
// -> launch_bounds(256,2) sits in the proven no-clamp no-spill regime (R2).
// LDS ring: 4 bufs x 8KB = 32KB/block (64KB/CU). bid&7=(nb<<2)|ks -> each XCD's
// blocks share one 2.1MB B slice (L2-resident). setprio(1) around the MFMA quad
// (T5: pays on phase-split schedules once co-tenant role diversity exists).
__global__ __launch_bounds__(256, 2) void k_gemm(const _Float16* __restrict__ Bp,
                                                 const _Float16* __restrict__ Xh,
                                                 const _Float16* __restrict__ LT,
                                                 float* __restrict__ parts) {
    __shared__ __align__(16) _Float16 Bs[4 * 4096];   // 32 KB: 4 bufs x (2 kt16 x 4 nt x 1KB)

    const int bid   = blockIdx.x;           // 512 blocks
    const int ks    = bid & 3;
    const int nb    = (bid >> 2) & 1;
    const int m_blk = bid >> 3;             // 0..63
    const int m0    = m_blk * 128;
    const int slab0 = (ks == 0) ? 0 : 33 + 32 * (ks - 1);
    const int nslab = (ks == 0) ? 33 : 32;  // 33 + 3*32 = 129

    const int tid = threadIdx.x, wid = tid >> 6, lane = tid & 63;
    const int l32 = lane & 31, khalf = lane >> 5;
    const int wm = wid >> 1, wn = wid & 1;  // 2M x 2N wave grid, tile 64x64
    const int mrow0 = m0 + wm * 64 + l32;   // row-tile 0
    const int mrow1 = mrow0 + 32;           // row-tile 1

    // ---- A fragment rows into registers (2 row-tiles x 16 k16-tiles x h8)
    h8 xv0[16], xv1[16];
    const _Float16* xp0 = Xh + (size_t)mrow0 * IN_N + khalf * 8;
    const _Float16* xp1 = Xh + (size_t)mrow1 * IN_N + khalf * 8;
#pragma unroll
    for (int k = 0; k < 16; ++k) {
        xv0[k] = *(const h8*)(xp0 + k * 16);
        xv1[k] = *(const h8*)(xp1 + k * 16);
    }

    // latent scalars for slab 0
    const _Float16* ltp = LT + (size_t)slab0 * BATCH;
    _Float16 sc0 = ltp[mrow0], sc1 = ltp[mrow1];

    // ---- B staging: 8 chunks/step (ktl in {0,1} x ntl in 0..3), 2 per wave.
    // Chunk c = ktl*4 + ntl; global nt = nb*4 + ntl.
    const int chunk0 = wid * 2;
    const char* Bgb = (const char*)Bp;

#define STAGE(bufidx, ktg)                                                                 \
    _Pragma("unroll")                                                                      \
    for (int i_ = 0; i_ < 2; ++i_) {                                                       \
        const int c_   = chunk0 + i_;                                                      \
        const int ktl_ = c_ >> 2, ntl_ = c_ & 3;                                           \
        const int ntg_ = nb * 4 + ntl_;                                                    \
        const char* g_ = Bgb + (((size_t)(ntg_ * KT16 + (ktg) + ktl_)) << 10) + (lane << 4);\
        _Float16* l_ = Bs + (bufidx) * 4096 + c_ * 512;                                    \
        __builtin_amdgcn_global_load_lds((const AS1 void*)g_, (AS3 void*)l_, 16, 0, 0);    \
    }

    f16v acc00, acc01, acc10, acc11;        // [row-tile][col-tile]
#pragma unroll
    for (int r = 0; r < 16; ++r) { acc00[r] = 0.f; acc01[r] = 0.f; acc10[r] = 0.f; acc11[r] = 0.f; }

#define KSTEP(bufc, sl)                                                                    \
    _Pragma("unroll")                                                                      \
    for (int j = 0; j < 2; ++j) {                                                          \
        const int kx = (((sl) * 2 + j) & 15);                                              \
        h8 a0 = xv0[kx] * s80;                                                             \
        h8 a1 = xv1[kx] * s81;                                                             \
        const _Float16* bb = Bs + (bufc) * 4096 + j * 2048 + wn * 1024 + (lane << 3);      \
        h8 b0 = *(const h8*)(bb);                                                          \
        h8 b1 = *(const h8*)(bb + 512);                                                    \
        __builtin_amdgcn_s_setprio(1);                                                     \
        acc00 = __builtin_amdgcn_mfma_f32_32x32x16_f16(a0, b0, acc00, 0, 0, 0);            \
        acc01 = __builtin_amdgcn_mfma_f32_32x32x16_f16(a0, b1, acc01, 0, 0, 0);            \
        acc10 = __builtin_amdgcn_mfma_f32_32x32x16_f16(a1, b0, acc10, 0, 0, 0);            \
        acc11 = __builtin_amdgcn_mfma_f32_32x32x16_f16(a1, b1, acc11, 0, 0, 0);            \
        __builtin_amdgcn_s_setprio(0);                                                     \
    }

    const int kb = slab0 * 16;              // base kt16 of this K-split

    // ---- prologue: stage steps 0,1 into bufs 0,1; wait buf0 complete (oldest 2 of 4)
    STAGE(0, kb + 0);
    STAGE(1, kb + 2);
    WAITVM2;
    __builtin_amdgcn_s_barrier();
    asm volatile("" ::: "memory");

    // ---- main loop: slabs 0 .. nslab-2 (8 steps/slab; stages always valid)
    for (int s0 = 0; s0 < nslab - 1; ++s0) {
        _Float16 sn0 = ltp[(size_t)(s0 + 1) * BATCH + mrow0];   // 2 VM ops (covered by WAITVM4)
        _Float16 sn1 = ltp[(size_t)(s0 + 1) * BATCH + mrow1];
        h8 s80, s81;
#pragma unroll
        for (int h = 0; h < 8; ++h) { s80[h] = sc0; s81[h] = sc1; }
        const int ktg0 = kb + s0 * 16;
#pragma unroll
        for (int sl = 0; sl < 8; ++sl) {
            STAGE((sl + 2) & 3, ktg0 + (sl + 2) * 2);
            KSTEP(sl & 3, sl);
            if (sl == 0) WAITVM4; else WAITVM2;
            __builtin_amdgcn_s_barrier();
            asm volatile("" ::: "memory");
        }
        sc0 = sn0; sc1 = sn1;
    }

    // ---- last slab (peeled): stages only for sl<6; drain at sl==6
    {
        h8 s80, s81;
#pragma unroll
        for (int h = 0; h < 8; ++h) { s80[h] = sc0; s81[h] = sc1; }
        const int ktg0 = kb + (nslab - 1) * 16;
#pragma unroll
        for (int sl = 0; sl < 8; ++sl) {
            if (sl < 6) STAGE((sl + 2) & 3, ktg0 + (sl + 2) * 2);
            KSTEP(sl & 3, sl);
            if (sl < 7) {
                if (sl == 6) WAITVM0; else WAITVM2;
                __builtin_amdgcn_s_barrier();
                asm volatile("" ::: "memory");
            }
        }
    }

    // ---- epilogue: write partials; split 0 accumulates onto pre-written bias
    float* dst = parts + (size_t)ks * ((size_t)BATCH * OUT_N);
    const int rowb0 = m0 + wm * 64;
#define EPI(rowb, u, accv)                                                                 \
    {                                                                                      \
        int col = nb * 128 + wn * 64 + (u) * 32 + l32;                                     \
        _Pragma("unroll")                                                                  \
        for (int r = 0; r < 16; ++r) {                                                     \
            int row = (rowb) + (r & 3) + 8 * (r >> 2) + 4 * khalf;                         \
            size_t off = (size_t)row * OUT_N + col;                                        \
            if (ks == 0) dst[off] += accv[r];                                              \
            else         dst[off] = accv[r];                                               \
        }                                                                                  \
    }
    EPI(rowb0,      0, acc00); EPI(rowb0,      1, acc01);
    EPI(rowb0 + 32, 0, acc10); EPI(rowb0 + 32, 1, acc11);
#undef EPI
#undef KSTEP
#undef STAGE
}

// ---------------- K3: out = sum of 4 partials
__global__ void k_reduce(const float* __restrict__ parts, float* __restrict__ out) {
    int i = (blockIdx.x * 256 + threadIdx.x) * 4;
    f4v s = *(const f4v*)(parts + i);
    s += *(const f4v*)(parts + 2097152 + i);
    s += *(const f4v*)(parts + 2 * 2097152 + i);
    s += *(const f4v*)(parts + 3 * 2097152 + i);
    *(f4v*)(out + i) = s;
}

extern "C" void kernel_launch(void* const* d_in, const int* in_sizes, int n_in,
                              void* d_out, int out_size, void* d_ws, size_t ws_size,
                              hipStream_t stream) {
    const float* x      = (const float*)d_in[0];
    const float* latent = (const float*)d_in[1];
    const float* Ww     = (const float*)d_in[2];
    const float* bw     = (const float*)d_in[3];
    const float* Wb     = (const float*)d_in[4];
    const float* bb     = (const float*)d_in[5];

    char* ws = (char*)d_ws;
    _Float16* Bp    = (_Float16*)(ws + WS_BP);
    _Float16* Xh    = (_Float16*)(ws + WS_XH);
    _Float16* LT    = (_Float16*)(ws + WS_LT);
    float*    parts = (float*)(ws + WS_PARTS);
    float*    out   = (float*)d_out;

    k_prep<<<PR_B1, 256, 0, stream>>>(Ww, bw, x, latent, Wb, bb, Bp, Xh, LT, parts);
    k_gemm<<<512, 256, 0, stream>>>(Bp, Xh, LT, parts);
    k_reduce<<<2048, 256, 0, stream>>>(parts, out);
}